// Round 10
// baseline (53.339 us; speedup 1.0000x reference)
//
#include <hip/hip_runtime.h>
#include <hip/hip_bf16.h>

#define NUM_OPS 8
#define D 1024
#define B_ROWS 8192

typedef unsigned short ushort_t;
typedef __attribute__((ext_vector_type(8))) short bf16x8;
typedef __attribute__((ext_vector_type(4))) float f32x4;
typedef __attribute__((ext_vector_type(4))) float float4v;
typedef __attribute__((ext_vector_type(8))) unsigned short ushort8;

__device__ __forceinline__ unsigned short f2bf(float f) {
    union { float f; unsigned int u; } v; v.f = f;
    unsigned int u = v.u;
    unsigned int lsb = (u >> 16) & 1u;
    u += 0x7fffu + lsb;   // round-to-nearest-even
    return (unsigned short)(u >> 16);
}

__device__ __forceinline__ void load_lds16(const void* g, void* l) {
    __builtin_amdgcn_global_load_lds(
        (const __attribute__((address_space(1))) void*)g,
        (__attribute__((address_space(3))) void*)l,
        16, 0, 0);
}

// deterministic top-2 (matches jax top_k tie-breaking: earliest index wins)
__device__ __forceinline__ void top2(const float* __restrict__ logits, int& i0, int& i1) {
    float best = -__builtin_inff(); i0 = 0;
    for (int i = 0; i < NUM_OPS; ++i) { float v = logits[i]; if (v > best) { best = v; i0 = i; } }
    float best2 = -__builtin_inff(); i1 = 0;
    for (int i = 0; i < NUM_OPS; ++i) {
        if (i == i0) continue;
        float v = logits[i]; if (v > best2) { best2 = v; i1 = i; }
    }
}

// ---------------- x : f32 -> bf16 (linear row-major) ----------------
__global__ void convert_x(const float* __restrict__ x, ushort_t* __restrict__ xb) {
    int i = (blockIdx.x * 256 + threadIdx.x) * 8;
    float4v v0 = *(const float4v*)(x + i);
    float4v v1 = *(const float4v*)(x + i + 4);
    ushort8 o;
    o[0] = f2bf(v0[0]); o[1] = f2bf(v0[1]); o[2] = f2bf(v0[2]); o[3] = f2bf(v0[3]);
    o[4] = f2bf(v1[0]); o[5] = f2bf(v1[1]); o[6] = f2bf(v1[2]); o[7] = f2bf(v1[3]);
    *(ushort8*)(xb + i) = o;
}

// ------- gather selected experts' W into MFMA B-fragment order -------------
// frag id fi = ((e*16 + P)*16 + u)*8 + c4*2 + kk   (P: 64-col panel, u: K-tile,
// c4: 16-col block, kk: K-half).  Wf byte (fi*1024 + lane*16 + 2j) holds
// W_e[u*64 + kk*32 + (lane>>4)*8 + j][P*64 + c4*16 + (lane&15)]
// => one e-chunk (8 frags) is 8 consecutive KB; loads are 16B/lane coalesced.
__global__ void gather_frag_W(const float* __restrict__ Ws,
                              const float* __restrict__ logits,
                              ushort_t* __restrict__ Wf) {
    __shared__ float t[32][33];
    int s0, s1; top2(logits, s0, s1);
    const int b  = blockIdx.x;              // ((e*32 + kt)*32 + nt)
    const int nt = b & 31, kt = (b >> 5) & 31, e = b >> 10;
    const int td = kt * 32, te = nt * 32;
    const int tx = threadIdx.x & 31, ty = threadIdx.x >> 5;
    const float* W = Ws + (size_t)(e ? s1 : s0) * D * D;
    #pragma unroll
    for (int r = 0; r < 4; ++r)
        t[ty + 8 * r][tx] = W[(size_t)(td + ty + 8 * r) * D + te + tx];
    __syncthreads();
    const int vid = threadIdx.x;
    if (vid < 128) {
        const int n_l = vid & 31, kg = vid >> 5;
        const int n = te + n_l, k0 = td + kg * 8;
        const int u = k0 >> 6, kk = (k0 >> 5) & 1, lq = (k0 >> 3) & 3;
        const int P = n >> 6, c4 = (n >> 4) & 3, l15 = n & 15;
        const int lane = lq * 16 + l15;
        const int fi = ((e * 16 + P) * 16 + u) * 8 + c4 * 2 + kk;
        ushort8 o;
        #pragma unroll
        for (int j = 0; j < 8; ++j) o[j] = f2bf(t[kg * 8 + j][n_l]);
        *(ushort8*)(Wf + (size_t)fi * 512 + lane * 8) = o;
    }
}

// -------- A staging: linear LDS dest, inverse-XOR-swizzled global source ---
// LDS tile [128 rows][64 cols] bf16; byte (r*128+c') holds col (c'^((r&7)<<4)).
__device__ __forceinline__ void stageA(const ushort_t* __restrict__ xbf, int brow,
                                       int u, ushort_t* dst, int tid) {
    #pragma unroll
    for (int q = 0; q < 4; ++q) {           // 128 rows x 128B = 16KB
        const int c   = q * 256 + tid;
        const int rr  = c >> 3;
        const int gcb = ((c & 7) * 16) ^ ((rr & 7) << 4);
        load_lds16(xbf + (size_t)(brow + rr) * D + u * 64 + (gcb >> 1), dst + c * 8);
    }
}

#define SB()    __builtin_amdgcn_sched_barrier(0)
#define PRIO1() __builtin_amdgcn_s_setprio(1)
#define PRIO0() __builtin_amdgcn_s_setprio(0)
#define VM(N)   do { asm volatile("s_waitcnt vmcnt(" #N ")" ::: "memory"); } while (0)

// read the 8 A fragments of tile u from LDS buffer CA
#define RD_A(CA)                                                                   \
    do {                                                                           \
        _Pragma("unroll") for (int kk = 0; kk < 2; ++kk)                           \
        _Pragma("unroll") for (int m = 0; m < 4; ++m)                              \
            a[kk][m] = *(const bf16x8*)((const char*)(CA) +                        \
                (size_t)((wr * 64 + m * 16 + l15) * 128) + (kk ? x1 : x0));        \
    } while (0)

// issue one e-chunk (8 consecutive 1KB frags) of B for K-tile u into SET
#define LD_B(SET, E, U)                                                            \
    do {                                                                           \
        const ushort_t* cb = Wf + ((size_t)(((E) * 16 + P) * 16 + (U)) * 8) * 512  \
                              + lane * 8;                                          \
        _Pragma("unroll") for (int i = 0; i < 8; ++i)                              \
            SET[i] = *(const bf16x8*)(cb + (size_t)i * 512);                       \
    } while (0)

// 32 MFMA for expert E against b-set SET (index c4*2+kk)
#define MM(E, SET)                                                                 \
    do {                                                                           \
        PRIO1();                                                                   \
        _Pragma("unroll") for (int kk = 0; kk < 2; ++kk)                           \
        _Pragma("unroll") for (int m = 0; m < 4; ++m)                              \
        _Pragma("unroll") for (int c4 = 0; c4 < 4; ++c4)                           \
            acc[E][m][c4] = __builtin_amdgcn_mfma_f32_16x16x32_bf16(               \
                a[kk][m], SET[c4 * 2 + kk], acc[E][m][c4], 0, 0, 0);               \
        PRIO0();                                                                   \
    } while (0)

// one K-tile: A from LDS, B e0 prefetched last tile (bX), e1 loaded now (bY),
// next tile's e0 issued mid-tile. Trailing counted VM leaves the newest
// {stage(u+2), bX-next} in flight across the raw barrier -- never vmcnt(0).
#define TILE(CA, DA, SU, U, VMN, DOSTG, DOBAR)                                     \
    do {                                                                           \
        RD_A(CA);                                                                  \
        LD_B(bY, 1, (U));                                                          \
        if (DOSTG) stageA(xbf, brow, (SU), DA, tid);                               \
        SB();                                                                      \
        MM(0, bX);                                                                 \
        if ((U) < 15) LD_B(bX, 0, (U) + 1);                                        \
        SB();                                                                      \
        MM(1, bY);                                                                 \
        VM(VMN);                                                                   \
        if (DOBAR) __builtin_amdgcn_s_barrier();                                   \
    } while (0)

// -------- fused dual-expert GEMM: high-intensity acc, hybrid A-LDS/B-direct -
// Block: 128 rows x 128 cols x 2 experts, 4 waves (2r x 2c). Wave tile:
// 64r x 64c x 2e -> acc[2][4][4] = 128 VGPR (85 FLOP per operand byte).
// A: LDS 3-buffer rotation (16KB/tile), counted vmcnt. B: direct global
// from fragment-ordered Wf (4MB, L2-resident), one e-chunk prefetch ahead.
__global__ __launch_bounds__(256, 2)
void gemm_dual(const ushort_t* __restrict__ xbf, const ushort_t* __restrict__ Wf,
               const float* __restrict__ bs, const float* __restrict__ logits,
               float* __restrict__ out) {
    __shared__ __align__(16) ushort_t As0[128 * 64], As1[128 * 64], As2[128 * 64];

    const int tid  = threadIdx.x;
    const int wv   = tid >> 6;
    const int lane = tid & 63;
    const int wr   = wv >> 1, wc = wv & 1;
    const int l15  = lane & 15, lq = lane >> 4;
    const int swz  = (l15 & 7) << 4;
    const int x0   = (lq * 16) ^ swz;
    const int x1   = (64 + lq * 16) ^ swz;

    // rows vary fastest: XCD x keeps row-stripes {x, x+8, ...} L2-resident
    const int bid  = blockIdx.x;
    const int brow = (bid & 63) * 128;
    const int P    = (bid >> 6) * 2 + wc;    // 64-col panel, 0..15

    f32x4  acc[2][4][4] = {};
    bf16x8 a[2][4];
    bf16x8 bX[8], bY[8];

    // prologue: stage A tiles 0,1; prefetch B(0).e0
    stageA(xbf, brow, 0, As0, tid);
    stageA(xbf, brow, 1, As1, tid);
    LD_B(bX, 0, 0);
    SB();
    VM(12);                       // A(0) staged; A(1)+bX stay in flight
    __builtin_amdgcn_s_barrier();

    TILE(As0, As2,  2,  0, 12, true,  true);
    TILE(As1, As0,  3,  1, 12, true,  true);
    TILE(As2, As1,  4,  2, 12, true,  true);
    TILE(As0, As2,  5,  3, 12, true,  true);
    TILE(As1, As0,  6,  4, 12, true,  true);
    TILE(As2, As1,  7,  5, 12, true,  true);
    TILE(As0, As2,  8,  6, 12, true,  true);
    TILE(As1, As0,  9,  7, 12, true,  true);
    TILE(As2, As1, 10,  8, 12, true,  true);
    TILE(As0, As2, 11,  9, 12, true,  true);
    TILE(As1, As0, 12, 10, 12, true,  true);
    TILE(As2, As1, 13, 11, 12, true,  true);
    TILE(As0, As2, 14, 12, 12, true,  true);
    TILE(As1, As0, 15, 13, 12, true,  true);
    TILE(As2, As1,  0, 14,  8, false, true);   // drain stage(15); keep bX
    TILE(As0, As1,  0, 15,  0, false, false);  // final tile

    // ---- epilogue: per-expert bias + relu, sum, store f32
    int s0, s1; top2(logits, s0, s1);
    #pragma unroll
    for (int c4 = 0; c4 < 4; ++c4) {
        const int col = P * 64 + c4 * 16 + l15;
        const float b0 = bs[s0 * D + col];
        const float b1 = bs[s1 * D + col];
        #pragma unroll
        for (int m = 0; m < 4; ++m) {
            const int rbase = brow + wr * 64 + m * 16 + lq * 4;
            #pragma unroll
            for (int i = 0; i < 4; ++i) {
                float v0 = acc[0][m][c4][i] + b0; v0 = v0 > 0.f ? v0 : 0.f;
                float v1 = acc[1][m][c4][i] + b1; v1 = v1 > 0.f ? v1 : 0.f;
                out[(size_t)(rbase + i) * D + col] = v0 + v1;
            }
        }
    }
}

extern "C" void kernel_launch(void* const* d_in, const int* in_sizes, int n_in,
                              void* d_out, int out_size, void* d_ws, size_t ws_size,
                              hipStream_t stream) {
    const float* x      = (const float*)d_in[0];
    const float* logits = (const float*)d_in[1];
    const float* Ws     = (const float*)d_in[2];
    const float* bs     = (const float*)d_in[3];
    float* out = (float*)d_out;

    char* ws = (char*)d_ws;
    ushort_t* xbf = (ushort_t*)ws;                                   // 16 MB
    ushort_t* Wf  = (ushort_t*)(ws + (size_t)B_ROWS * D * 2);        //  4 MB

    convert_x<<<(B_ROWS * D) / (256 * 8), 256, 0, stream>>>(x, xbf);
    gather_frag_W<<<2 * 32 * 32, 256, 0, stream>>>(Ws, logits, Wf);

    gemm_dual<<<512, 256, 0, stream>>>(xbf, Wf, bs, logits, out);
}